// Round 16
// baseline (369.775 us; speedup 1.0000x reference)
//
#include <hip/hip_runtime.h>
#include <hip/hip_bf16.h>

typedef __attribute__((ext_vector_type(8))) short bf16x8;
typedef __attribute__((ext_vector_type(4))) float f32x4;

__device__ __forceinline__ float sigm(float x) {
    return __builtin_amdgcn_rcpf(1.0f + __expf(-x));
}
__device__ __forceinline__ float tanh_(float x) {
    float e = __expf(2.0f * x);
    return 1.0f - 2.0f * __builtin_amdgcn_rcpf(e + 1.0f);
}
__device__ __forceinline__ ushort f2bf(float f) {   // RNE float->bf16
    uint u = __float_as_uint(f);
    u = u + 0x7FFFu + ((u >> 16) & 1u);
    return (ushort)(u >> 16);
}
__device__ __forceinline__ float bf2f(ushort s) { return __uint_as_float(((uint)s) << 16); }

// ====== FULLY PIPELINED: e1(MFMA) ∥ e2 ∥ d1 ∥ d2 in ONE barrier loop, + fc ======
// R14 lesson: fused kernel = e1 phase (~106 prof) + decoder tail (~84 prof, 4/16
// waves active). Fix: skewed software pipeline. At iteration it:
//   e1 step it (it<96, all 16 waves; wave15 e2-xg tile -> pe2[it-1], incl. it=96)
//   e2 step it-2 (wave 4, lanes 0-15)  [pe2[s] written it=s+1, visible it>=s+2]
//   d1 step it-3 (threads 0-255, R6 math, weights from LDS w_d1)
//   d2 step it-5 (wave 5, lanes 0-15)  [pd2[s] written it=s+4 by d1 step s+1]
// One __syncthreads per iteration separates every producer->consumer pair —
// identical visibility discipline to R14, arithmetic identical, just reordered.
// Decoder chains are independent of e1's chain -> fill its latency bubbles.
// Drain: iterations 96..132 run decoder only (~37 light iterations), then fc.
// LDS ~142KB (adds w_d1[64][20]); 1 block/CU as before.
__global__ __launch_bounds__(1024) __attribute__((amdgpu_waves_per_eu(4, 4)))
void fused_all(
    const float* __restrict__ x,
    const float* __restrict__ e1_Wih, const float* __restrict__ e1_Whh, const float* __restrict__ e1_b,
    const float* __restrict__ e2_Wih, const float* __restrict__ e2_b,
    const float* __restrict__ e2_Whh,
    const float* __restrict__ d1_Wih, const float* __restrict__ d1_Whh, const float* __restrict__ d1_b,
    const float* __restrict__ d2_Wih, const float* __restrict__ d2_b,
    const float* __restrict__ d2_Whh,
    const float* __restrict__ fc1_W, const float* __restrict__ fc1_b,
    const float* __restrict__ fc2_W, const float* __restrict__ fc2_b,
    float* __restrict__ out)
{
    __shared__ float x_s[16 * 772];                      // 49.4 KB
    __shared__ __align__(16) ushort h_hi[2][8][16][8];   // 4 KB
    __shared__ __align__(16) ushort h_lo[2][8][16][8];   // 4 KB
    __shared__ __align__(16) ushort x2_s[2][4][16][8];   // 2 KB
    __shared__ __align__(16) float pe2_s[96 * 64];       // 24 KB
    __shared__ float din_s[16][132];                     // 8.4 KB
    __shared__ float h_lds[16][16];                      // 1 KB
    __shared__ float pd2_s[16 * 516];                    // 33 KB
    __shared__ float d2h_s[16 * 132];                    // 8.4 KB
    __shared__ float mid_s[16 * 36];                     // 2.3 KB
    __shared__ float w_d1[64][20];                       // 5 KB: whh[16], wih, b

    const int t = threadIdx.x;
    const int bBase = blockIdx.x * 16;
    const int wv = t >> 6, l = t & 63;
    const int row = l & 15, sub = l >> 4;

    // ---- stage x ----
    for (int bb = 0; bb < 16; ++bb)
        for (int i = t; i < 768; i += 1024)
            x_s[bb * 772 + i] = x[(size_t)(bBase + bb) * 768 + i];

    // ---- preload d1 weights into LDS ----
    for (int i = t; i < 64 * 18; i += 1024) {
        int r = i / 18, j = i - r * 18;
        w_d1[r][j] = (j < 16) ? d1_Whh[r * 16 + j] : ((j == 16) ? d1_Wih[r] : d1_b[r]);
    }

    // ---- A fragments (e1 weights, hi/lo bf16) — loop-invariant ----
    auto loadW = [&](const float* rowbase, int k0, bool valid, bf16x8& hi8, bf16x8& lo8) {
        float f[8];
        if (valid) {
            float4 v0 = ((const float4*)(rowbase + k0))[0];
            float4 v1 = ((const float4*)(rowbase + k0))[1];
            f[0]=v0.x; f[1]=v0.y; f[2]=v0.z; f[3]=v0.w;
            f[4]=v1.x; f[5]=v1.y; f[6]=v1.z; f[7]=v1.w;
        } else {
            #pragma unroll
            for (int j = 0; j < 8; ++j) f[j] = 0.f;
        }
        #pragma unroll
        for (int j = 0; j < 8; ++j) {
            ushort h = f2bf(f[j]);
            hi8[j] = (short)h;
            lo8[j] = (short)f2bf(f[j] - bf2f(h));
        }
    };
    auto loadA = [&](int T, bool isE2, bf16x8& Ah0, bf16x8& Ah1, bf16x8& Al0, bf16x8& Al1, bf16x8& A2) {
        const int gate = row & 3, uq = row >> 2;
        const bool valid = !isE2 || (uq == 0);
        const int wr = isE2 ? gate : gate * 64 + T * 4 + uq;
        const float* rp = isE2 ? (e2_Wih + (size_t)wr * 64) : (e1_Whh + (size_t)wr * 64);
        loadW(rp, sub * 8,      valid, Ah0, Al0);
        loadW(rp, 32 + sub * 8, valid, Ah1, Al1);
        #pragma unroll
        for (int j = 0; j < 8; ++j) A2[j] = 0;
        if (valid) {
            if (!isE2) {
                if (sub < 3) {
                    const float* wihr = e1_Wih + (size_t)wr * 8;
                    #pragma unroll
                    for (int j = 0; j < 8; ++j) {
                        float f = wihr[j];
                        ushort hh = f2bf(f);
                        A2[j] = (sub < 2) ? (short)hh : (short)f2bf(f - bf2f(hh));
                    }
                } else {
                    float bb = e1_b[wr];
                    ushort hh = f2bf(bb);
                    A2[0] = (short)hh; A2[1] = (short)f2bf(bb - bf2f(hh));
                }
            } else if (sub == 3) {
                float bb = e2_b[wr];
                ushort hh = f2bf(bb);
                A2[0] = (short)hh; A2[1] = (short)f2bf(bb - bf2f(hh));
            }
        }
    };

    bf16x8 A0h0, A0h1, A0l0, A0l1, A0x;
    bf16x8 A2h0, A2h1, A2l0, A2l1, A2x;
    loadA(wv, false, A0h0, A0h1, A0l0, A0l1, A0x);
    if (wv == 15) loadA(0, true, A2h0, A2h1, A2l0, A2l1, A2x);

    __syncthreads();   // x_s + w_d1 ready

    // ---- init h parity0, x2 both parities, x_aux -> din_s rows 96..127 ----
    if (t < 1024) { ((ushort*)h_hi[0])[t] = 0; ((ushort*)h_lo[0])[t] = 0; }
    if (t < 384) {
        int sb = t >> 7, b = (t >> 3) & 15, j = t & 7;
        float xv = x_s[b * 772 + j];
        ushort hi = f2bf(xv);
        x2_s[0][sb][b][j] = (sb == 1) ? f2bf(xv - bf2f(hi)) : hi;
        x2_s[1][sb][b][j] = 0;
    } else if (t < 512) {
        int b = (t >> 3) & 15, j = t & 7;
        ushort v = (j < 2) ? (ushort)0x3F80 : (ushort)0;
        x2_s[0][3][b][j] = v;
        x2_s[1][3][b][j] = v;
    }
    if (wv >= 1 && wv <= 8) {
        int i = (wv - 1) * 64 + l;
        int B = i >> 5, j = i & 31;
        din_s[B][96 + j] = x_s[B * 772 + (64 + j) * 8];
    }

    // ---- persistent states / statics ----
    const int cb = l & 15;
    const int u0_ = wv * 4 + sub;
    float c0r = 0.f;                                   // e1 cell

    const float e2w0 = e2_Whh[0], e2w1 = e2_Whh[1], e2w2 = e2_Whh[2], e2w3 = e2_Whh[3];
    float h_e2 = 0.f, c_e2 = 0.f;                      // e2 recurrence (wave 4)

    const float d2r0 = d2_Whh[0], d2r1 = d2_Whh[1], d2r2 = d2_Whh[2], d2r3 = d2_Whh[3];
    float h_d2 = 0.f, c_d2 = 0.f;                      // d2 recurrence (wave 5)

    const int dw = t >> 6, dlane = t & 63;
    const int dq = dlane >> 4, du = dlane & 15;
    const int drow = dw * 4 + dq;                      // d1: batch 0..15 (t<256)
    float d2w[16];
    float d2bias = 0.f;
    if (t < 256) {
        const float4* wp = (const float4*)(d2_Wih + (size_t)(du & 3) * 16);
        #pragma unroll
        for (int k4 = 0; k4 < 4; ++k4) {
            float4 v = wp[k4];
            d2w[4*k4+0] = v.x; d2w[4*k4+1] = v.y; d2w[4*k4+2] = v.z; d2w[4*k4+3] = v.w;
        }
        d2bias = d2_b[du & 3];
    }
    float c_d1 = 0.f;                                  // d1 cell (t<256)

    __syncthreads();

    // =================== pipelined main loop: 133 iterations ===================
    #pragma unroll 1
    for (int it = 0; it < 133; ++it) {
        const int p = it & 1, pn = p ^ 1;

        // ---------- e1 step it (+ wave15 e2-xg tile through it=96) ----------
        if (it <= 96) {
            bf16x8 Bh0 = *(const bf16x8*)&h_hi[p][sub][cb][0];
            bf16x8 Bh1 = *(const bf16x8*)&h_hi[p][4 + sub][cb][0];
            bf16x8 Bl0 = *(const bf16x8*)&h_lo[p][sub][cb][0];
            bf16x8 Bl1 = *(const bf16x8*)&h_lo[p][4 + sub][cb][0];
            bf16x8 Bx  = *(const bf16x8*)&x2_s[p][sub][cb][0];

            if (it < 96) {
                f32x4 u0 = {0.f,0.f,0.f,0.f}, v0 = {0.f,0.f,0.f,0.f};
                u0 = __builtin_amdgcn_mfma_f32_16x16x32_bf16(A0h0, Bh0, u0, 0, 0, 0);
                u0 = __builtin_amdgcn_mfma_f32_16x16x32_bf16(A0l0, Bh0, u0, 0, 0, 0);
                u0 = __builtin_amdgcn_mfma_f32_16x16x32_bf16(A0h0, Bl0, u0, 0, 0, 0);
                v0 = __builtin_amdgcn_mfma_f32_16x16x32_bf16(A0h1, Bh1, v0, 0, 0, 0);
                v0 = __builtin_amdgcn_mfma_f32_16x16x32_bf16(A0l1, Bh1, v0, 0, 0, 0);
                v0 = __builtin_amdgcn_mfma_f32_16x16x32_bf16(A0h1, Bl1, v0, 0, 0, 0);
                v0 = __builtin_amdgcn_mfma_f32_16x16x32_bf16(A0x,  Bx,  v0, 0, 0, 0);

                f32x4 acc = u0 + v0;
                c0r = fmaf(sigm(acc[1]), c0r, sigm(acc[0]) * tanh_(acc[2]));
                float hv = sigm(acc[3]) * tanh_(c0r);
                ushort hh = f2bf(hv);
                h_hi[pn][u0_ >> 3][cb][u0_ & 7] = hh;
                h_lo[pn][u0_ >> 3][cb][u0_ & 7] = f2bf(hv - bf2f(hh));
            }
            if (wv == 15) {
                f32x4 u2 = {0.f,0.f,0.f,0.f}, v2 = {0.f,0.f,0.f,0.f};
                u2 = __builtin_amdgcn_mfma_f32_16x16x32_bf16(A2h0, Bh0, u2, 0, 0, 0);
                u2 = __builtin_amdgcn_mfma_f32_16x16x32_bf16(A2l0, Bh0, u2, 0, 0, 0);
                u2 = __builtin_amdgcn_mfma_f32_16x16x32_bf16(A2h0, Bl0, u2, 0, 0, 0);
                v2 = __builtin_amdgcn_mfma_f32_16x16x32_bf16(A2h1, Bh1, v2, 0, 0, 0);
                v2 = __builtin_amdgcn_mfma_f32_16x16x32_bf16(A2l1, Bh1, v2, 0, 0, 0);
                v2 = __builtin_amdgcn_mfma_f32_16x16x32_bf16(A2h1, Bl1, v2, 0, 0, 0);
                v2 = __builtin_amdgcn_mfma_f32_16x16x32_bf16(A2x,  Bx,  v2, 0, 0, 0);
                if (it > 0 && sub == 0) {
                    f32x4 acc2 = u2 + v2;
                    #pragma unroll
                    for (int i = 0; i < 4; ++i)
                        pe2_s[(it - 1) * 64 + i * 16 + cb] = acc2[i];
                }
            }
            if (it < 95 && t < 384) {
                int sb = t >> 7, b = (t >> 3) & 15, j = t & 7;
                float xv = x_s[b * 772 + (it + 1) * 8 + j];
                ushort hi = f2bf(xv);
                x2_s[pn][sb][b][j] = (sb == 1) ? f2bf(xv - bf2f(hi)) : hi;
            }
        }

        // ---------- e2 recurrence step it-2 (wave 4, lanes 0-15) ----------
        if (wv == 4 && l < 16 && it >= 2 && it <= 97) {
            int s = it - 2;
            float gi = pe2_s[s * 64 + l];
            float gf = pe2_s[s * 64 + 16 + l];
            float gg = pe2_s[s * 64 + 32 + l];
            float go = pe2_s[s * 64 + 48 + l];
            gi = fmaf(h_e2, e2w0, gi);
            gf = fmaf(h_e2, e2w1, gf);
            gg = fmaf(h_e2, e2w2, gg);
            go = fmaf(h_e2, e2w3, go);
            c_e2 = fmaf(sigm(gf), c_e2, sigm(gi) * tanh_(gg));
            h_e2 = sigm(go) * tanh_(c_e2);
            din_s[l][s] = fmaxf(h_e2, 0.f);
        }

        // ---------- d1 step it-3 (threads 0-255) ----------
        if (t < 256 && it >= 3 && it <= 130) {
            int s = it - 3;
            float xv = din_s[drow][s];
            // weights from LDS (rows g*16+du; [16]=wih, [17]=bias)
            float wg0[16], wg1[16], wg2[16], wg3[16];
            {
                const float4* w0p = (const float4*)&w_d1[du][0];
                const float4* w1p = (const float4*)&w_d1[16 + du][0];
                const float4* w2p = (const float4*)&w_d1[32 + du][0];
                const float4* w3p = (const float4*)&w_d1[48 + du][0];
                #pragma unroll
                for (int k4 = 0; k4 < 4; ++k4) {
                    float4 a = w0p[k4]; wg0[4*k4+0]=a.x; wg0[4*k4+1]=a.y; wg0[4*k4+2]=a.z; wg0[4*k4+3]=a.w;
                    float4 b = w1p[k4]; wg1[4*k4+0]=b.x; wg1[4*k4+1]=b.y; wg1[4*k4+2]=b.z; wg1[4*k4+3]=b.w;
                    float4 c4 = w2p[k4]; wg2[4*k4+0]=c4.x; wg2[4*k4+1]=c4.y; wg2[4*k4+2]=c4.z; wg2[4*k4+3]=c4.w;
                    float4 d4 = w3p[k4]; wg3[4*k4+0]=d4.x; wg3[4*k4+1]=d4.y; wg3[4*k4+2]=d4.z; wg3[4*k4+3]=d4.w;
                }
            }
            float p0 = fmaf(xv, w_d1[du][16],      w_d1[du][17]);
            float p1 = fmaf(xv, w_d1[16 + du][16], w_d1[16 + du][17]);
            float p2 = fmaf(xv, w_d1[32 + du][16], w_d1[32 + du][17]);
            float p3 = fmaf(xv, w_d1[48 + du][16], w_d1[48 + du][17]);
            if (s > 0) {
                float hv[16];
                const float4* hp = (const float4*)&h_lds[drow][0];
                #pragma unroll
                for (int k4 = 0; k4 < 4; ++k4) {
                    float4 v = hp[k4];
                    hv[4*k4+0] = v.x; hv[4*k4+1] = v.y; hv[4*k4+2] = v.z; hv[4*k4+3] = v.w;
                }
                #pragma unroll
                for (int k = 0; k < 16; ++k) {
                    p0 = fmaf(hv[k], wg0[k], p0);
                    p1 = fmaf(hv[k], wg1[k], p1);
                    p2 = fmaf(hv[k], wg2[k], p2);
                    p3 = fmaf(hv[k], wg3[k], p3);
                }
                if (du < 4) {
                    float a = d2bias;
                    #pragma unroll
                    for (int k = 0; k < 16; ++k) a = fmaf(hv[k], d2w[k], a);
                    pd2_s[drow * 516 + (s - 1) * 4 + du] = a;
                }
            }
            c_d1 = fmaf(sigm(p1), c_d1, sigm(p0) * tanh_(p2));
            float h = sigm(p3) * tanh_(c_d1);
            h_lds[drow][du] = h;
        }
        if (t < 256 && it == 131) {   // final d2-xg (step 127)
            float hv[16];
            const float4* hp = (const float4*)&h_lds[drow][0];
            #pragma unroll
            for (int k4 = 0; k4 < 4; ++k4) {
                float4 v = hp[k4];
                hv[4*k4+0] = v.x; hv[4*k4+1] = v.y; hv[4*k4+2] = v.z; hv[4*k4+3] = v.w;
            }
            if (du < 4) {
                float a = d2bias;
                #pragma unroll
                for (int k = 0; k < 16; ++k) a = fmaf(hv[k], d2w[k], a);
                pd2_s[drow * 516 + 127 * 4 + du] = a;
            }
        }

        // ---------- d2 recurrence step it-5 (wave 5, lanes 0-15) ----------
        if (wv == 5 && l < 16 && it >= 5) {
            int s = it - 5;
            float4 g4 = *(const float4*)&pd2_s[l * 516 + s * 4];
            float gi = fmaf(h_d2, d2r0, g4.x);
            float gf = fmaf(h_d2, d2r1, g4.y);
            float gg = fmaf(h_d2, d2r2, g4.z);
            float go = fmaf(h_d2, d2r3, g4.w);
            c_d2 = fmaf(sigm(gf), c_d2, sigm(gi) * tanh_(gg));
            h_d2 = sigm(go) * tanh_(c_d2);
            d2h_s[l * 132 + s] = h_d2;
        }

        __syncthreads();
    }

    // =================== fc1 (128->32) + fc2 (32->32) ===================
    if (t < 256) {
        const int bb = t >> 4, o = t & 15;
        float acc0 = fc1_b[o], acc1 = fc1_b[o + 16];
        const float4* wa = (const float4*)(fc1_W + (size_t)o * 128);
        const float4* wb = (const float4*)(fc1_W + (size_t)(o + 16) * 128);
        const float4* fp = (const float4*)&d2h_s[bb * 132];
        #pragma unroll
        for (int k4 = 0; k4 < 32; ++k4) {
            float4 f = fp[k4], va = wa[k4], vb = wb[k4];
            acc0 = fmaf(f.x, va.x, acc0); acc0 = fmaf(f.y, va.y, acc0);
            acc0 = fmaf(f.z, va.z, acc0); acc0 = fmaf(f.w, va.w, acc0);
            acc1 = fmaf(f.x, vb.x, acc1); acc1 = fmaf(f.y, vb.y, acc1);
            acc1 = fmaf(f.z, vb.z, acc1); acc1 = fmaf(f.w, vb.w, acc1);
        }
        mid_s[bb * 36 + o] = acc0;
        mid_s[bb * 36 + o + 16] = acc1;
    }
    __syncthreads();
    if (t < 256) {
        const int bb = t >> 4, o = t & 15;
        float o0 = fc2_b[o], o1 = fc2_b[o + 16];
        const float4* va2 = (const float4*)(fc2_W + (size_t)o * 32);
        const float4* vb2 = (const float4*)(fc2_W + (size_t)(o + 16) * 32);
        const float4* mp = (const float4*)&mid_s[bb * 36];
        #pragma unroll
        for (int k4 = 0; k4 < 8; ++k4) {
            float4 m = mp[k4], va = va2[k4], vb = vb2[k4];
            o0 = fmaf(m.x, va.x, o0); o0 = fmaf(m.y, va.y, o0);
            o0 = fmaf(m.z, va.z, o0); o0 = fmaf(m.w, va.w, o0);
            o1 = fmaf(m.x, vb.x, o1); o1 = fmaf(m.y, vb.y, o1);
            o1 = fmaf(m.z, vb.z, o1); o1 = fmaf(m.w, vb.w, o1);
        }
        out[((size_t)bBase + bb) * 32 + o] = o0;
        out[((size_t)bBase + bb) * 32 + o + 16] = o1;
    }
}

extern "C" void kernel_launch(void* const* d_in, const int* in_sizes, int n_in,
                              void* d_out, int out_size, void* d_ws, size_t ws_size,
                              hipStream_t stream) {
    const float* x      = (const float*)d_in[0];
    const float* e1_Wih = (const float*)d_in[1];
    const float* e1_Whh = (const float*)d_in[2];
    const float* e1_b   = (const float*)d_in[3];
    const float* e2_Wih = (const float*)d_in[4];
    const float* e2_Whh = (const float*)d_in[5];
    const float* e2_b   = (const float*)d_in[6];
    const float* d1_Wih = (const float*)d_in[7];
    const float* d1_Whh = (const float*)d_in[8];
    const float* d1_b   = (const float*)d_in[9];
    const float* d2_Wih = (const float*)d_in[10];
    const float* d2_Whh = (const float*)d_in[11];
    const float* d2_b   = (const float*)d_in[12];
    const float* fc1_W  = (const float*)d_in[13];
    const float* fc1_b  = (const float*)d_in[14];
    const float* fc2_W  = (const float*)d_in[15];
    const float* fc2_b  = (const float*)d_in[16];
    float* out = (float*)d_out;

    hipLaunchKernelGGL(fused_all, dim3(256), dim3(1024), 0, stream,
                       x, e1_Wih, e1_Whh, e1_b, e2_Wih, e2_b, e2_Whh,
                       d1_Wih, d1_Whh, d1_b, d2_Wih, d2_b, d2_Whh,
                       fc1_W, fc1_b, fc2_W, fc2_b, out);
}

// Round 17
// 149.692 us; speedup vs baseline: 2.4702x; 2.4702x over previous
//
#include <hip/hip_runtime.h>
#include <hip/hip_bf16.h>

typedef __attribute__((ext_vector_type(8))) short bf16x8;
typedef __attribute__((ext_vector_type(4))) float f32x4;

__device__ __forceinline__ float sigm(float x) {
    return __builtin_amdgcn_rcpf(1.0f + __expf(-x));
}
__device__ __forceinline__ float tanh_(float x) {
    float e = __expf(2.0f * x);
    return 1.0f - 2.0f * __builtin_amdgcn_rcpf(e + 1.0f);
}
__device__ __forceinline__ ushort f2bf(float f) {   // RNE float->bf16
    uint u = __float_as_uint(f);
    u = u + 0x7FFFu + ((u >> 16) & 1u);
    return (ushort)(u >> 16);
}
__device__ __forceinline__ float bf2f(ushort s) { return __uint_as_float(((uint)s) << 16); }

// ============ FUSED: e1(MFMA) + e2 + decoder(d1+d2+fc), one kernel (R14, best @150us) ============
// R15's software pipeline spilled (110MB scratch writes: d1 weights live alongside
// e1 fragments exceeded the 128-VGPR budget) -> reverted to the phase-sequential
// fused form where phase-1 and phase-2 register live ranges are disjoint.
// Phase 1 = R10 k1_enc (16 waves x 1 tile, swapped-operand MFMA, fused e2 xg +
// recurrence), dec_in in LDS. Phase 2 = R6 decoder on threads 0-255.
__global__ __launch_bounds__(1024) __attribute__((amdgpu_waves_per_eu(4, 4)))
void fused_all(
    const float* __restrict__ x,
    const float* __restrict__ e1_Wih, const float* __restrict__ e1_Whh, const float* __restrict__ e1_b,
    const float* __restrict__ e2_Wih, const float* __restrict__ e2_b,
    const float* __restrict__ e2_Whh,
    const float* __restrict__ d1_Wih, const float* __restrict__ d1_Whh, const float* __restrict__ d1_b,
    const float* __restrict__ d2_Wih, const float* __restrict__ d2_b,
    const float* __restrict__ d2_Whh,
    const float* __restrict__ fc1_W, const float* __restrict__ fc1_b,
    const float* __restrict__ fc2_W, const float* __restrict__ fc2_b,
    float* __restrict__ out)
{
    // phase-1 arrays
    __shared__ float x_s[16 * 772];                      // 49.4 KB
    __shared__ __align__(16) ushort h_hi[2][8][16][8];   // 4 KB
    __shared__ __align__(16) ushort h_lo[2][8][16][8];   // 4 KB
    __shared__ __align__(16) ushort x2_s[2][4][16][8];   // 2 KB
    __shared__ __align__(16) float pe2_s[96 * 64];       // 24 KB
    // bridge + phase-2 arrays
    __shared__ float din_s[16][132];                     // 8.4 KB
    __shared__ float h_lds[16][16];                      // 1 KB
    __shared__ float pd2_s[16 * 516];                    // 33 KB
    __shared__ float d2h_s[16 * 132];                    // 8.4 KB
    __shared__ float mid_s[16 * 36];                     // 2.3 KB

    const int t = threadIdx.x;
    const int bBase = blockIdx.x * 16;
    const int wv = t >> 6, l = t & 63;
    const int row = l & 15, sub = l >> 4;

    // ---- stage x ----
    for (int bb = 0; bb < 16; ++bb)
        for (int i = t; i < 768; i += 1024)
            x_s[bb * 772 + i] = x[(size_t)(bBase + bb) * 768 + i];

    // ---- A fragments (weights, hi/lo bf16) — loop-invariant ----
    auto loadW = [&](const float* rowbase, int k0, bool valid, bf16x8& hi8, bf16x8& lo8) {
        float f[8];
        if (valid) {
            float4 v0 = ((const float4*)(rowbase + k0))[0];
            float4 v1 = ((const float4*)(rowbase + k0))[1];
            f[0]=v0.x; f[1]=v0.y; f[2]=v0.z; f[3]=v0.w;
            f[4]=v1.x; f[5]=v1.y; f[6]=v1.z; f[7]=v1.w;
        } else {
            #pragma unroll
            for (int j = 0; j < 8; ++j) f[j] = 0.f;
        }
        #pragma unroll
        for (int j = 0; j < 8; ++j) {
            ushort h = f2bf(f[j]);
            hi8[j] = (short)h;
            lo8[j] = (short)f2bf(f[j] - bf2f(h));
        }
    };
    auto loadA = [&](int T, bool isE2, bf16x8& Ah0, bf16x8& Ah1, bf16x8& Al0, bf16x8& Al1, bf16x8& A2) {
        const int gate = row & 3, uq = row >> 2;
        const bool valid = !isE2 || (uq == 0);
        const int wr = isE2 ? gate : gate * 64 + T * 4 + uq;
        const float* rp = isE2 ? (e2_Wih + (size_t)wr * 64) : (e1_Whh + (size_t)wr * 64);
        loadW(rp, sub * 8,      valid, Ah0, Al0);
        loadW(rp, 32 + sub * 8, valid, Ah1, Al1);
        #pragma unroll
        for (int j = 0; j < 8; ++j) A2[j] = 0;
        if (valid) {
            if (!isE2) {
                if (sub < 3) {
                    const float* wihr = e1_Wih + (size_t)wr * 8;
                    #pragma unroll
                    for (int j = 0; j < 8; ++j) {
                        float f = wihr[j];
                        ushort hh = f2bf(f);
                        A2[j] = (sub < 2) ? (short)hh : (short)f2bf(f - bf2f(hh));
                    }
                } else {
                    float bb = e1_b[wr];
                    ushort hh = f2bf(bb);
                    A2[0] = (short)hh; A2[1] = (short)f2bf(bb - bf2f(hh));
                }
            } else if (sub == 3) {
                float bb = e2_b[wr];
                ushort hh = f2bf(bb);
                A2[0] = (short)hh; A2[1] = (short)f2bf(bb - bf2f(hh));
            }
        }
    };

    bf16x8 A0h0, A0h1, A0l0, A0l1, A0x;
    bf16x8 A2h0, A2h1, A2l0, A2l1, A2x;
    loadA(wv, false, A0h0, A0h1, A0l0, A0l1, A0x);
    if (wv == 15) loadA(0, true, A2h0, A2h1, A2l0, A2l1, A2x);

    __syncthreads();   // x_s ready

    if (t < 1024) { ((ushort*)h_hi[0])[t] = 0; ((ushort*)h_lo[0])[t] = 0; }
    if (t < 384) {
        int sb = t >> 7, b = (t >> 3) & 15, j = t & 7;
        float xv = x_s[b * 772 + j];
        ushort hi = f2bf(xv);
        x2_s[0][sb][b][j] = (sb == 1) ? f2bf(xv - bf2f(hi)) : hi;
        x2_s[1][sb][b][j] = 0;
    } else if (t < 512) {
        int b = (t >> 3) & 15, j = t & 7;
        ushort v = (j < 2) ? (ushort)0x3F80 : (ushort)0;
        x2_s[0][3][b][j] = v;
        x2_s[1][3][b][j] = v;
    }

    const int cb = l & 15;
    const int u0_ = wv * 4 + sub;
    float c0r = 0.f;
    __syncthreads();

    // =================== e1 main loop (R10, frozen) ===================
    #pragma unroll 1
    for (int ts = 0; ts < 96; ++ts) {
        const int p = ts & 1, pn = p ^ 1;

        bf16x8 Bh0 = *(const bf16x8*)&h_hi[p][sub][cb][0];
        bf16x8 Bh1 = *(const bf16x8*)&h_hi[p][4 + sub][cb][0];
        bf16x8 Bl0 = *(const bf16x8*)&h_lo[p][sub][cb][0];
        bf16x8 Bl1 = *(const bf16x8*)&h_lo[p][4 + sub][cb][0];
        bf16x8 Bx  = *(const bf16x8*)&x2_s[p][sub][cb][0];

        f32x4 u0 = {0.f,0.f,0.f,0.f}, v0 = {0.f,0.f,0.f,0.f};
        u0 = __builtin_amdgcn_mfma_f32_16x16x32_bf16(A0h0, Bh0, u0, 0, 0, 0);
        u0 = __builtin_amdgcn_mfma_f32_16x16x32_bf16(A0l0, Bh0, u0, 0, 0, 0);
        u0 = __builtin_amdgcn_mfma_f32_16x16x32_bf16(A0h0, Bl0, u0, 0, 0, 0);
        v0 = __builtin_amdgcn_mfma_f32_16x16x32_bf16(A0h1, Bh1, v0, 0, 0, 0);
        v0 = __builtin_amdgcn_mfma_f32_16x16x32_bf16(A0l1, Bh1, v0, 0, 0, 0);
        v0 = __builtin_amdgcn_mfma_f32_16x16x32_bf16(A0h1, Bl1, v0, 0, 0, 0);
        v0 = __builtin_amdgcn_mfma_f32_16x16x32_bf16(A0x,  Bx,  v0, 0, 0, 0);

        if (wv == 15) {
            f32x4 u2 = {0.f,0.f,0.f,0.f}, v2 = {0.f,0.f,0.f,0.f};
            u2 = __builtin_amdgcn_mfma_f32_16x16x32_bf16(A2h0, Bh0, u2, 0, 0, 0);
            u2 = __builtin_amdgcn_mfma_f32_16x16x32_bf16(A2l0, Bh0, u2, 0, 0, 0);
            u2 = __builtin_amdgcn_mfma_f32_16x16x32_bf16(A2h0, Bl0, u2, 0, 0, 0);
            v2 = __builtin_amdgcn_mfma_f32_16x16x32_bf16(A2h1, Bh1, v2, 0, 0, 0);
            v2 = __builtin_amdgcn_mfma_f32_16x16x32_bf16(A2l1, Bh1, v2, 0, 0, 0);
            v2 = __builtin_amdgcn_mfma_f32_16x16x32_bf16(A2h1, Bl1, v2, 0, 0, 0);
            v2 = __builtin_amdgcn_mfma_f32_16x16x32_bf16(A2x,  Bx,  v2, 0, 0, 0);
            if (ts > 0 && sub == 0) {
                f32x4 acc2 = u2 + v2;
                #pragma unroll
                for (int i = 0; i < 4; ++i)
                    pe2_s[(ts - 1) * 64 + i * 16 + cb] = acc2[i];
            }
        }

        {
            f32x4 acc = u0 + v0;
            c0r = fmaf(sigm(acc[1]), c0r, sigm(acc[0]) * tanh_(acc[2]));
            float hv = sigm(acc[3]) * tanh_(c0r);
            ushort hh = f2bf(hv);
            h_hi[pn][u0_ >> 3][cb][u0_ & 7] = hh;
            h_lo[pn][u0_ >> 3][cb][u0_ & 7] = f2bf(hv - bf2f(hh));
        }

        if (ts < 95 && t < 384) {
            int sb = t >> 7, b = (t >> 3) & 15, j = t & 7;
            float xv = x_s[b * 772 + (ts + 1) * 8 + j];
            ushort hi = f2bf(xv);
            x2_s[pn][sb][b][j] = (sb == 1) ? f2bf(xv - bf2f(hi)) : hi;
        }
        __syncthreads();
    }

    // ---- pe2[95] from final h (parity 0) ----
    if (wv == 15) {
        bf16x8 Bh0 = *(const bf16x8*)&h_hi[0][sub][cb][0];
        bf16x8 Bh1 = *(const bf16x8*)&h_hi[0][4 + sub][cb][0];
        bf16x8 Bl0 = *(const bf16x8*)&h_lo[0][sub][cb][0];
        bf16x8 Bl1 = *(const bf16x8*)&h_lo[0][4 + sub][cb][0];
        bf16x8 Bx  = *(const bf16x8*)&x2_s[0][sub][cb][0];
        f32x4 u2 = {0.f,0.f,0.f,0.f}, v2 = {0.f,0.f,0.f,0.f};
        u2 = __builtin_amdgcn_mfma_f32_16x16x32_bf16(A2h0, Bh0, u2, 0, 0, 0);
        u2 = __builtin_amdgcn_mfma_f32_16x16x32_bf16(A2l0, Bh0, u2, 0, 0, 0);
        u2 = __builtin_amdgcn_mfma_f32_16x16x32_bf16(A2h0, Bl0, u2, 0, 0, 0);
        v2 = __builtin_amdgcn_mfma_f32_16x16x32_bf16(A2h1, Bh1, v2, 0, 0, 0);
        v2 = __builtin_amdgcn_mfma_f32_16x16x32_bf16(A2l1, Bh1, v2, 0, 0, 0);
        v2 = __builtin_amdgcn_mfma_f32_16x16x32_bf16(A2h1, Bl1, v2, 0, 0, 0);
        v2 = __builtin_amdgcn_mfma_f32_16x16x32_bf16(A2x,  Bx,  v2, 0, 0, 0);
        if (sub == 0) {
            f32x4 acc2 = u2 + v2;
            #pragma unroll
            for (int i = 0; i < 4; ++i)
                pe2_s[95 * 64 + i * 16 + cb] = acc2[i];
        }
    }
    __syncthreads();

    // ---- fused e2 recurrence -> din_s rows 0..95; x_aux -> rows 96..127 ----
    if (wv == 0 && l < 16) {
        const float w0 = e2_Whh[0], w1 = e2_Whh[1], w2 = e2_Whh[2], w3 = e2_Whh[3];
        float ni = pe2_s[l], nf = pe2_s[16 + l], ng = pe2_s[32 + l], no = pe2_s[48 + l];
        float h = 0.f, c = 0.f;
        #pragma unroll 1
        for (int ts = 0; ts < 96; ++ts) {
            float gi = ni, gf = nf, gg2 = ng, go = no;
            if (ts < 95) {
                int b2 = (ts + 1) * 64;
                ni = pe2_s[b2 + l]; nf = pe2_s[b2 + 16 + l];
                ng = pe2_s[b2 + 32 + l]; no = pe2_s[b2 + 48 + l];
            }
            gi = fmaf(h, w0, gi);
            gf = fmaf(h, w1, gf);
            gg2 = fmaf(h, w2, gg2);
            go = fmaf(h, w3, go);
            c = fmaf(sigm(gf), c, sigm(gi) * tanh_(gg2));
            h = sigm(go) * tanh_(c);
            din_s[l][ts] = fmaxf(h, 0.f);
        }
    }
    if (wv >= 1 && wv <= 8) {
        int i = (wv - 1) * 64 + l;
        int B = i >> 5, j = i & 31;
        din_s[B][96 + j] = x_s[B * 772 + (64 + j) * 8];
    }
    __syncthreads();   // din_s ready for decoder

    // =================== Phase 2: R6 decoder on threads 0-255 ===================
    {
        const int dw = t >> 6, dlane = t & 63;       // dw 0..3 used
        const int dq = dlane >> 4, du = dlane & 15;
        const int drow = dw * 4 + dq;                // batch 0..15

        if (t < 256) {
            float wih_g[4], bg[4], whh_g[4][16], d2w[16];
            #pragma unroll
            for (int g = 0; g < 4; ++g) {
                wih_g[g] = d1_Wih[g * 16 + du];
                bg[g]    = d1_b[g * 16 + du];
                const float4* wp = (const float4*)(d1_Whh + (size_t)(g * 16 + du) * 16);
                #pragma unroll
                for (int k4 = 0; k4 < 4; ++k4) {
                    float4 v = wp[k4];
                    whh_g[g][4*k4+0] = v.x; whh_g[g][4*k4+1] = v.y;
                    whh_g[g][4*k4+2] = v.z; whh_g[g][4*k4+3] = v.w;
                }
            }
            {
                const float4* wp = (const float4*)(d2_Wih + (size_t)(du & 3) * 16);
                #pragma unroll
                for (int k4 = 0; k4 < 4; ++k4) {
                    float4 v = wp[k4];
                    d2w[4*k4+0] = v.x; d2w[4*k4+1] = v.y; d2w[4*k4+2] = v.z; d2w[4*k4+3] = v.w;
                }
            }
            const float d2bias = d2_b[du & 3];

            float h = 0.f, c = 0.f;
            float hv[16];
            #pragma unroll 1
            for (int ts = 0; ts < 128; ++ts) {
                float xv = din_s[drow][ts];
                float p0 = fmaf(xv, wih_g[0], bg[0]);
                float p1 = fmaf(xv, wih_g[1], bg[1]);
                float p2 = fmaf(xv, wih_g[2], bg[2]);
                float p3 = fmaf(xv, wih_g[3], bg[3]);
                if (ts > 0) {
                    const float4* hp = (const float4*)&h_lds[drow][0];
                    #pragma unroll
                    for (int k4 = 0; k4 < 4; ++k4) {
                        float4 v = hp[k4];
                        hv[4*k4+0] = v.x; hv[4*k4+1] = v.y; hv[4*k4+2] = v.z; hv[4*k4+3] = v.w;
                    }
                    #pragma unroll
                    for (int k = 0; k < 16; ++k) {
                        p0 = fmaf(hv[k], whh_g[0][k], p0);
                        p1 = fmaf(hv[k], whh_g[1][k], p1);
                        p2 = fmaf(hv[k], whh_g[2][k], p2);
                        p3 = fmaf(hv[k], whh_g[3][k], p3);
                    }
                    if (du < 4) {
                        float a = d2bias;
                        #pragma unroll
                        for (int k = 0; k < 16; ++k) a = fmaf(hv[k], d2w[k], a);
                        pd2_s[drow * 516 + (ts - 1) * 4 + du] = a;
                    }
                }
                c = fmaf(sigm(p1), c, sigm(p0) * tanh_(p2));
                h = sigm(p3) * tanh_(c);
                h_lds[drow][du] = h;
            }
            {
                const float4* hp = (const float4*)&h_lds[drow][0];
                #pragma unroll
                for (int k4 = 0; k4 < 4; ++k4) {
                    float4 v = hp[k4];
                    hv[4*k4+0] = v.x; hv[4*k4+1] = v.y; hv[4*k4+2] = v.z; hv[4*k4+3] = v.w;
                }
                if (du < 4) {
                    float a = d2bias;
                    #pragma unroll
                    for (int k = 0; k < 16; ++k) a = fmaf(hv[k], d2w[k], a);
                    pd2_s[drow * 516 + 127 * 4 + du] = a;
                }
            }
        }
        __syncthreads();

        // ---- d2 recurrence: 16 lanes, depth-4 register prefetch ----
        if (t < 16) {
            const float w0 = d2_Whh[0], w1 = d2_Whh[1], w2 = d2_Whh[2], w3 = d2_Whh[3];
            float4 dbuf[4];
            #pragma unroll
            for (int j = 0; j < 4; ++j) dbuf[j] = *(const float4*)&pd2_s[t * 516 + j * 4];
            float h2 = 0.f, c2 = 0.f;
            #pragma unroll
            for (int ts = 0; ts < 128; ++ts) {
                float4 g4 = dbuf[ts & 3];
                if (ts + 4 < 128) dbuf[ts & 3] = *(const float4*)&pd2_s[t * 516 + (ts + 4) * 4];
                float gi = fmaf(h2, w0, g4.x);
                float gf = fmaf(h2, w1, g4.y);
                float gg = fmaf(h2, w2, g4.z);
                float go = fmaf(h2, w3, g4.w);
                c2 = fmaf(sigm(gf), c2, sigm(gi) * tanh_(gg));
                h2 = sigm(go) * tanh_(c2);
                d2h_s[t * 132 + ts] = h2;
            }
        }
        __syncthreads();

        // ---- fc1 (128->32) ----
        if (t < 256) {
            const int bb = t >> 4, o = t & 15;
            float acc0 = fc1_b[o], acc1 = fc1_b[o + 16];
            const float4* wa = (const float4*)(fc1_W + (size_t)o * 128);
            const float4* wb = (const float4*)(fc1_W + (size_t)(o + 16) * 128);
            const float4* fp = (const float4*)&d2h_s[bb * 132];
            #pragma unroll
            for (int k4 = 0; k4 < 32; ++k4) {
                float4 f = fp[k4], va = wa[k4], vb = wb[k4];
                acc0 = fmaf(f.x, va.x, acc0); acc0 = fmaf(f.y, va.y, acc0);
                acc0 = fmaf(f.z, va.z, acc0); acc0 = fmaf(f.w, va.w, acc0);
                acc1 = fmaf(f.x, vb.x, acc1); acc1 = fmaf(f.y, vb.y, acc1);
                acc1 = fmaf(f.z, vb.z, acc1); acc1 = fmaf(f.w, vb.w, acc1);
            }
            mid_s[bb * 36 + o] = acc0;
            mid_s[bb * 36 + o + 16] = acc1;
        }
        __syncthreads();

        // ---- fc2 (32->32) ----
        if (t < 256) {
            const int bb = t >> 4, o = t & 15;
            float o0 = fc2_b[o], o1 = fc2_b[o + 16];
            const float4* va2 = (const float4*)(fc2_W + (size_t)o * 32);
            const float4* vb2 = (const float4*)(fc2_W + (size_t)(o + 16) * 32);
            const float4* mp = (const float4*)&mid_s[bb * 36];
            #pragma unroll
            for (int k4 = 0; k4 < 8; ++k4) {
                float4 m = mp[k4], va = va2[k4], vb = vb2[k4];
                o0 = fmaf(m.x, va.x, o0); o0 = fmaf(m.y, va.y, o0);
                o0 = fmaf(m.z, va.z, o0); o0 = fmaf(m.w, va.w, o0);
                o1 = fmaf(m.x, vb.x, o1); o1 = fmaf(m.y, vb.y, o1);
                o1 = fmaf(m.z, vb.z, o1); o1 = fmaf(m.w, vb.w, o1);
            }
            out[((size_t)bBase + bb) * 32 + o] = o0;
            out[((size_t)bBase + bb) * 32 + o + 16] = o1;
        }
    }
}

extern "C" void kernel_launch(void* const* d_in, const int* in_sizes, int n_in,
                              void* d_out, int out_size, void* d_ws, size_t ws_size,
                              hipStream_t stream) {
    const float* x      = (const float*)d_in[0];
    const float* e1_Wih = (const float*)d_in[1];
    const float* e1_Whh = (const float*)d_in[2];
    const float* e1_b   = (const float*)d_in[3];
    const float* e2_Wih = (const float*)d_in[4];
    const float* e2_Whh = (const float*)d_in[5];
    const float* e2_b   = (const float*)d_in[6];
    const float* d1_Wih = (const float*)d_in[7];
    const float* d1_Whh = (const float*)d_in[8];
    const float* d1_b   = (const float*)d_in[9];
    const float* d2_Wih = (const float*)d_in[10];
    const float* d2_Whh = (const float*)d_in[11];
    const float* d2_b   = (const float*)d_in[12];
    const float* fc1_W  = (const float*)d_in[13];
    const float* fc1_b  = (const float*)d_in[14];
    const float* fc2_W  = (const float*)d_in[15];
    const float* fc2_b  = (const float*)d_in[16];
    float* out = (float*)d_out;

    hipLaunchKernelGGL(fused_all, dim3(256), dim3(1024), 0, stream,
                       x, e1_Wih, e1_Whh, e1_b, e2_Wih, e2_b, e2_Whh,
                       d1_Wih, d1_Whh, d1_b, d2_Wih, d2_b, d2_Whh,
                       fc1_W, fc1_b, fc2_W, fc2_b, out);
}